// Round 3
// baseline (4744.868 us; speedup 1.0000x reference)
//
#include <hip/hip_runtime.h>
#include <hip/hip_bf16.h>
#include <stdint.h>

// Problem dims
#define Bx  128
#define Tt  1024
#define INx 256
#define Hx  512
#define RB  16           // batch rows per group
#define RING 8           // h0/h1 ring slots
#define LSTR 520         // LDS A-row stride in fp16 (512 + 8 pad)
#define RSLOT (Bx*Hx)    // ring slot elements (fp16)

// s_getreg encoding: ID | (offset<<6) | ((size-1)<<11); ID_XCC_ID = 20 (gfx94x/gfx950)
#define HWREG_XCC_ID_ENC (20 | (0 << 6) | (31 << 11))

typedef _Float16 half8 __attribute__((ext_vector_type(8)));
typedef float float4v __attribute__((ext_vector_type(4)));

__device__ __forceinline__ float sigf(float x) { return 1.0f / (1.0f + expf(-x)); }

__device__ __forceinline__ half8 cvt8(const float* __restrict__ p) {
    float4v f0 = *(const float4v*)(p);
    float4v f1 = *(const float4v*)(p + 4);
    half8 a;
    a[0] = (_Float16)f0[0]; a[1] = (_Float16)f0[1];
    a[2] = (_Float16)f0[2]; a[3] = (_Float16)f0[3];
    a[4] = (_Float16)f1[0]; a[5] = (_Float16)f1[1];
    a[6] = (_Float16)f1[2]; a[7] = (_Float16)f1[3];
    return a;
}

__device__ __forceinline__ void vm0() { asm volatile("s_waitcnt vmcnt(0)" ::: "memory"); }

// h-data path.
// L2M=true : all 32 blocks of this group share one XCD -> plain store lands in
//            that XCD's L2 (L1 is write-through); sc0 load bypasses L1, hits L2.
// L2M=false: MALL-coherent (sc0 sc1) -- correct for any placement (baseline).
template<bool L2M>
__device__ __forceinline__ half8 ldq(const _Float16* p) {
    half8 v;
    if (L2M) asm volatile("global_load_dwordx4 %0, %1, off sc0"       : "=v"(v) : "v"(p) : "memory");
    else     asm volatile("global_load_dwordx4 %0, %1, off sc0 sc1"   : "=v"(v) : "v"(p) : "memory");
    return v;
}
template<bool L2M>
__device__ __forceinline__ void stw(void* p, unsigned v) {
    if (L2M) asm volatile("global_store_dword %0, %1, off"            :: "v"(p), "v"(v) : "memory");
    else     asm volatile("global_store_dword %0, %1, off sc0 sc1"    :: "v"(p), "v"(v) : "memory");
}

// Flags: ALWAYS agent-scope atomics at MALL (the proven baseline protocol).
__device__ __forceinline__ unsigned ldctr(const unsigned* p) {
    return __hip_atomic_load(p, __ATOMIC_RELAXED, __HIP_MEMORY_SCOPE_AGENT);
}
__device__ __forceinline__ void stflag(unsigned* p, unsigned v) {
    __hip_atomic_store(p, v, __ATOMIC_RELAXED, __HIP_MEMORY_SCOPE_AGENT);
}

// wave-0 poll: lanes [0,n0) require b0[lane] >= t0 ; lanes [16,16+n1) require b1[lane-16] >= t1
__device__ __forceinline__ void pollge(const unsigned* b0, unsigned t0, int n0,
                                       const unsigned* b1, unsigned t1, int n1, int lane) {
    const unsigned* p = nullptr; unsigned t = 0; int act = 0;
    if (lane < n0)                          { p = b0 + lane;        t = t0; act = 1; }
    else if (lane >= 16 && lane < 16 + n1)  { p = b1 + (lane - 16); t = t1; act = 1; }
    for (;;) {
        int ok = 1;
        if (act) ok = (ldctr(p) >= t);
        if (__all(ok)) break;
        __builtin_amdgcn_s_sleep(1);
    }
}

// A-read once, two MFMAs (2 unit-tiles) per K-chunk.
template<int NC, int NA>
__device__ __forceinline__ void mfma2(const _Float16* buf, int arow, int koff,
                                      const half8 (&B0)[NA], const half8 (&B1)[NA],
                                      float4v& a0, float4v& a1) {
    #pragma unroll
    for (int c = 0; c < NC; ++c) {
        half8 a = *(const half8*)(buf + arow + c * 32 + koff);
        a0 = __builtin_amdgcn_mfma_f32_16x16x32_f16(a, B0[c], a0, 0, 0, 0);
        a1 = __builtin_amdgcn_mfma_f32_16x16x32_f16(a, B1[c], a1, 0, 0, 0);
    }
}

// ws word layout: [0]=startup barrier, [32..287]=xcc map,
// [512..767]=flags (8 groups x {16 L0, 16 L1}; value = last finished step + 1).
// zero_ctr re-zeroes everything at the start of every replay.
__global__ void zero_ctr(unsigned* __restrict__ p) {
    for (int i = threadIdx.x; i < 1024; i += 512)
        __hip_atomic_store(&p[i], 0u, __ATOMIC_RELAXED, __HIP_MEMORY_SCOPE_AGENT);
}

template<bool L2M>
__device__ void run_lstm(
    int g, int id, int tid,
    const float* __restrict__ x,
    const float* __restrict__ w_ih_l0, const float* __restrict__ w_hh_l0,
    const float* __restrict__ b_ih_l0, const float* __restrict__ b_hh_l0,
    const float* __restrict__ w_ih_l1, const float* __restrict__ w_hh_l1,
    const float* __restrict__ b_ih_l1, const float* __restrict__ b_hh_l1,
    unsigned* __restrict__ syncw, _Float16* __restrict__ h0r, _Float16* __restrict__ h1r,
    _Float16* bufX, _Float16* bufH, float (*gbuf)[RB][33])
{
    const int L   = id & 1;
    const int ub  = id >> 1;
    const int u0  = ub * 32;
    const int grow = g * RB;

    const int wv   = tid >> 6;      // gate wave
    const int lane = tid & 63;
    const int n    = lane & 15;
    const int quad = lane >> 4;
    const int koff = quad * 8;
    const int arow = n * LSTR;
    const int srow = tid >> 4;      // staging/update row 0..15
    const int sc   = tid & 15;      // staging col / update unit-pair

    unsigned* flags = syncw + 512;
    unsigned* fl0 = flags + g * 32;           // layer-0 flags [16]
    unsigned* fl1 = flags + g * 32 + 16;      // layer-1 flags [16]
    unsigned* myf = flags + g * 32 + L * 16 + ub;

    // biases for this thread's 2 update units, all 4 gates
    const float* bi = L ? b_ih_l1 : b_ih_l0;
    const float* bh = L ? b_hh_l1 : b_hh_l0;
    float bias[4][2];
    #pragma unroll
    for (int q = 0; q < 4; ++q)
        #pragma unroll
        for (int j = 0; j < 2; ++j) {
            int u = q * Hx + u0 + 2 * sc + j;
            bias[q][j] = bi[u] + bh[u];
        }

    float cs0 = 0.0f, cs1 = 0.0f;   // cell states for the 2 update units

    if (L == 0) {
        // -------- layer 0 --------
        half8 W1a[8], W1b[8], W2a[16], W2b[16];
        const int wrA = wv * Hx + u0 + n, wrB = wrA + 16;
        #pragma unroll
        for (int c = 0; c < 8; ++c) {
            W1a[c] = cvt8(w_ih_l0 + (size_t)wrA * INx + c * 32 + koff);
            W1b[c] = cvt8(w_ih_l0 + (size_t)wrB * INx + c * 32 + koff);
        }
        #pragma unroll
        for (int c = 0; c < 16; ++c) {
            W2a[c] = cvt8(w_hh_l0 + (size_t)wrA * Hx + c * 32 + koff);
            W2b[c] = cvt8(w_hh_l0 + (size_t)wrB * Hx + c * 32 + koff);
        }

        for (int s = 0; s < Tt; ++s) {
            // stage x_s (cached loads; before the poll barrier)
            {
                const float* xp = x + ((size_t)(grow + srow) * Tt + s) * INx + sc * 16;
                float4v x0 = *(const float4v*)(xp);
                float4v x1 = *(const float4v*)(xp + 4);
                float4v x2 = *(const float4v*)(xp + 8);
                float4v x3 = *(const float4v*)(xp + 12);
                half8 hA, hB;
                hA[0]=(_Float16)x0[0]; hA[1]=(_Float16)x0[1]; hA[2]=(_Float16)x0[2]; hA[3]=(_Float16)x0[3];
                hA[4]=(_Float16)x1[0]; hA[5]=(_Float16)x1[1]; hA[6]=(_Float16)x1[2]; hA[7]=(_Float16)x1[3];
                hB[0]=(_Float16)x2[0]; hB[1]=(_Float16)x2[1]; hB[2]=(_Float16)x2[2]; hB[3]=(_Float16)x2[3];
                hB[4]=(_Float16)x3[0]; hB[5]=(_Float16)x3[1]; hB[6]=(_Float16)x3[2]; hB[7]=(_Float16)x3[3];
                *(half8*)(bufX + srow * LSTR + sc * 16)     = hA;
                *(half8*)(bufX + srow * LSTR + sc * 16 + 8) = hB;
            }
            __syncthreads();                                 // (a) bufX ready
            float4v a0 = {0.f,0.f,0.f,0.f}, a1 = {0.f,0.f,0.f,0.f};
            if (wv != 0) {
                mfma2<8>(bufX, arow, koff, W1a, W1b, a0, a1); // overlap with wave-0 poll
            } else {
                int n0 = (s > 0) ? 16 : 0;                    // peers produced h0[s-1]
                int n1 = (((s & 3) == 0) && s >= 8) ? 16 : 0; // ring guard: L1 finished s-5
                pollge(fl0, (unsigned)s, n0, fl1, (unsigned)(s - 4), n1, lane);
            }
            __syncthreads();                                 // (b) h0[s-1] visible
            if (s > 0) {
                const _Float16* hp = h0r + (size_t)((s - 1) & 7) * RSLOT
                                   + (size_t)(grow + srow) * Hx + sc * 32;
                half8 v0 = ldq<L2M>(hp), v1 = ldq<L2M>(hp + 8),
                      v2 = ldq<L2M>(hp + 16), v3 = ldq<L2M>(hp + 24);
                if (wv == 0) mfma2<8>(bufX, arow, koff, W1a, W1b, a0, a1); // under load latency
                vm0();
                *(half8*)(bufH + srow * LSTR + sc * 32)      = v0;
                *(half8*)(bufH + srow * LSTR + sc * 32 + 8)  = v1;
                *(half8*)(bufH + srow * LSTR + sc * 32 + 16) = v2;
                *(half8*)(bufH + srow * LSTR + sc * 32 + 24) = v3;
                __syncthreads();                             // (c)
                mfma2<16>(bufH, arow, koff, W2a, W2b, a0, a1);
            } else if (wv == 0) {
                mfma2<8>(bufX, arow, koff, W1a, W1b, a0, a1);
            }
            #pragma unroll
            for (int r = 0; r < 4; ++r) {
                gbuf[wv][quad * 4 + r][n]      = a0[r];
                gbuf[wv][quad * 4 + r][16 + n] = a1[r];
            }
            __syncthreads();                                 // (d)
            {
                unsigned pv = 0;
                #pragma unroll
                for (int j = 0; j < 2; ++j) {
                    float iv = gbuf[0][srow][2 * sc + j] + bias[0][j];
                    float fv = gbuf[1][srow][2 * sc + j] + bias[1][j];
                    float gv = gbuf[2][srow][2 * sc + j] + bias[2][j];
                    float ov = gbuf[3][srow][2 * sc + j] + bias[3][j];
                    float& cc = j ? cs1 : cs0;
                    float cn = sigf(fv) * cc + sigf(iv) * tanhf(gv);
                    cc = cn;
                    _Float16 hn = (_Float16)(sigf(ov) * tanhf(cn));
                    pv |= (unsigned)__builtin_bit_cast(unsigned short, hn) << (16 * j);
                }
                stw<L2M>(h0r + (size_t)(s & 7) * RSLOT + (size_t)(grow + srow) * Hx + u0 + 2 * sc, pv);
            }
            vm0();                                           // stores ack'd (L2 in L2M mode)
            __syncthreads();                                 // (e)
            if (tid == 0) stflag(myf, (unsigned)(s + 1));    // flag via MALL (proven path)
        }
    } else {
        // -------- layer 1 --------
        half8 W1a[16], W1b[16], W2a[16], W2b[16];
        const int wrA = wv * Hx + u0 + n, wrB = wrA + 16;
        #pragma unroll
        for (int c = 0; c < 16; ++c) {
            W1a[c] = cvt8(w_ih_l1 + (size_t)wrA * Hx + c * 32 + koff);
            W1b[c] = cvt8(w_ih_l1 + (size_t)wrB * Hx + c * 32 + koff);
            W2a[c] = cvt8(w_hh_l1 + (size_t)wrA * Hx + c * 32 + koff);
            W2b[c] = cvt8(w_hh_l1 + (size_t)wrB * Hx + c * 32 + koff);
        }

        for (int s = 0; s < Tt; ++s) {
            // phase 1: h0[s] (L0 runs ahead -- usually ready immediately)
            if (wv == 0) pollge(fl0, (unsigned)(s + 1), 16, nullptr, 0u, 0, lane);
            __syncthreads();                                 // (a)
            {
                const _Float16* hp0 = h0r + (size_t)(s & 7) * RSLOT
                                    + (size_t)(grow + srow) * Hx + sc * 32;
                half8 v0 = ldq<L2M>(hp0), v1 = ldq<L2M>(hp0 + 8),
                      v2 = ldq<L2M>(hp0 + 16), v3 = ldq<L2M>(hp0 + 24);
                vm0();
                *(half8*)(bufX + srow * LSTR + sc * 32)      = v0;
                *(half8*)(bufX + srow * LSTR + sc * 32 + 8)  = v1;
                *(half8*)(bufX + srow * LSTR + sc * 32 + 16) = v2;
                *(half8*)(bufX + srow * LSTR + sc * 32 + 24) = v3;
            }
            __syncthreads();                                 // (b)
            float4v a0 = {0.f,0.f,0.f,0.f}, a1 = {0.f,0.f,0.f,0.f};
            if (wv != 0) {
                mfma2<16>(bufX, arow, koff, W1a, W1b, a0, a1); // overlap with h1-wait
            } else if (s > 0) {
                pollge(fl1, (unsigned)s, 16, nullptr, 0u, 0, lane); // peers made h1[s-1]
            }
            __syncthreads();                                 // (c)
            if (s > 0) {
                const _Float16* hp1 = h1r + (size_t)((s - 1) & 7) * RSLOT
                                    + (size_t)(grow + srow) * Hx + sc * 32;
                half8 w0 = ldq<L2M>(hp1), w1 = ldq<L2M>(hp1 + 8),
                      w2 = ldq<L2M>(hp1 + 16), w3 = ldq<L2M>(hp1 + 24);
                if (wv == 0) mfma2<16>(bufX, arow, koff, W1a, W1b, a0, a1);
                vm0();
                *(half8*)(bufH + srow * LSTR + sc * 32)      = w0;
                *(half8*)(bufH + srow * LSTR + sc * 32 + 8)  = w1;
                *(half8*)(bufH + srow * LSTR + sc * 32 + 16) = w2;
                *(half8*)(bufH + srow * LSTR + sc * 32 + 24) = w3;
                __syncthreads();                             // (d)
                mfma2<16>(bufH, arow, koff, W2a, W2b, a0, a1);
            } else if (wv == 0) {
                mfma2<16>(bufX, arow, koff, W1a, W1b, a0, a1);
            }
            #pragma unroll
            for (int r = 0; r < 4; ++r) {
                gbuf[wv][quad * 4 + r][n]      = a0[r];
                gbuf[wv][quad * 4 + r][16 + n] = a1[r];
            }
            __syncthreads();                                 // (e)
            {
                unsigned pv = 0;
                #pragma unroll
                for (int j = 0; j < 2; ++j) {
                    float iv = gbuf[0][srow][2 * sc + j] + bias[0][j];
                    float fv = gbuf[1][srow][2 * sc + j] + bias[1][j];
                    float gv = gbuf[2][srow][2 * sc + j] + bias[2][j];
                    float ov = gbuf[3][srow][2 * sc + j] + bias[3][j];
                    float& cc = j ? cs1 : cs0;
                    float cn = sigf(fv) * cc + sigf(iv) * tanhf(gv);
                    cc = cn;
                    _Float16 hn = (_Float16)(sigf(ov) * tanhf(cn));
                    pv |= (unsigned)__builtin_bit_cast(unsigned short, hn) << (16 * j);
                }
                _Float16* dst = h1r + (size_t)(s & 7) * RSLOT + (size_t)(grow + srow) * Hx + u0 + 2 * sc;
                if (s == Tt - 1) stw<false>(dst, pv);   // final slot: MALL so fc_kernel sees it
                else             stw<L2M>(dst, pv);
            }
            vm0();
            __syncthreads();                                 // (f)
            if (tid == 0) stflag(myf, (unsigned)(s + 1));
        }
    }
}

// Persistent LSTM: 256 blocks x 256 threads (4 waves), 1 block/CU.
// Startup: every block reads XCC_ID (builtin s_getreg), publishes it,
// grid-barriers once, and all blocks deterministically compute the same
// grouping from the shared map. If every XCD holds exactly 32 blocks,
// group = XCD and the h-data exchange runs through that XCD's L2;
// otherwise fall back to the MALL data path. Flags always via MALL.
__global__ __launch_bounds__(256, 1) void lstm_persist(
    const float* __restrict__ x,
    const float* __restrict__ w_ih_l0, const float* __restrict__ w_hh_l0,
    const float* __restrict__ b_ih_l0, const float* __restrict__ b_hh_l0,
    const float* __restrict__ w_ih_l1, const float* __restrict__ w_hh_l1,
    const float* __restrict__ b_ih_l1, const float* __restrict__ b_hh_l1,
    unsigned* __restrict__ syncw,
    _Float16* __restrict__ h0r, _Float16* __restrict__ h1r)
{
    __shared__ _Float16 bufX[RB * LSTR];   // 16.6 KB
    __shared__ _Float16 bufH[RB * LSTR];   // 16.6 KB
    __shared__ float gbuf[4][RB][33];      // 8.4 KB
    __shared__ unsigned smap[256];         // 1 KB
    __shared__ int sh_g, sh_id, sh_valid;

    const int tid = threadIdx.x;
    const int blk = blockIdx.x;

    const unsigned xcc = (unsigned)__builtin_amdgcn_s_getreg(HWREG_XCC_ID_ENC) & 7u;

    if (tid == 0) {
        __hip_atomic_store(&syncw[32 + blk], xcc, __ATOMIC_RELAXED, __HIP_MEMORY_SCOPE_AGENT);
        __hip_atomic_fetch_add(&syncw[0], 1u, __ATOMIC_RELEASE, __HIP_MEMORY_SCOPE_AGENT);
        while (__hip_atomic_load(&syncw[0], __ATOMIC_ACQUIRE, __HIP_MEMORY_SCOPE_AGENT) < 256u)
            __builtin_amdgcn_s_sleep(2);
    }
    __syncthreads();
    smap[tid] = __hip_atomic_load(&syncw[32 + tid], __ATOMIC_RELAXED, __HIP_MEMORY_SCOPE_AGENT);
    __syncthreads();
    if (tid == 0) {
        int cnt[8] = {0,0,0,0,0,0,0,0};
        int rank = 0;
        for (int i = 0; i < 256; ++i) {
            int m = (int)(smap[i] & 7u);
            cnt[m]++;
            if (i < blk && m == (int)xcc) rank++;
        }
        int ok = 1;
        #pragma unroll
        for (int i = 0; i < 8; ++i) ok &= (cnt[i] == 32);
        sh_valid = ok;
        sh_g  = ok ? (int)xcc : (blk >> 5);
        sh_id = ok ? rank : (blk & 31);
    }
    __syncthreads();

    if (sh_valid)
        run_lstm<true >(sh_g, sh_id, tid, x, w_ih_l0, w_hh_l0, b_ih_l0, b_hh_l0,
                        w_ih_l1, w_hh_l1, b_ih_l1, b_hh_l1, syncw, h0r, h1r,
                        bufX, bufH, gbuf);
    else
        run_lstm<false>(sh_g, sh_id, tid, x, w_ih_l0, w_hh_l0, b_ih_l0, b_hh_l0,
                        w_ih_l1, w_hh_l1, b_ih_l1, b_hh_l1, syncw, h0r, h1r,
                        bufX, bufH, gbuf);
}

// FC head; final h1 slot was stored sc0 sc1 (MALL), read with agent atomics.
__global__ __launch_bounds__(64) void fc_kernel(
    const _Float16* __restrict__ h1,
    const float* __restrict__ fc_w, const float* __restrict__ fc_b,
    const float* __restrict__ fc2_w, const float* __restrict__ fc2_b,
    float* __restrict__ out)
{
    const int b = blockIdx.x;
    const int j = threadIdx.x;
    const _Float16* h = h1 + (size_t)b * Hx;
    const float* w = fc_w + (size_t)j * Hx;
    float acc = fc_b[j];
    for (int k = 0; k < Hx; k += 2) {
        unsigned pv = __hip_atomic_load((const unsigned*)(h + k),
                                        __ATOMIC_RELAXED, __HIP_MEMORY_SCOPE_AGENT);
        _Float16 lo = __builtin_bit_cast(_Float16, (unsigned short)(pv & 0xffffu));
        _Float16 hi = __builtin_bit_cast(_Float16, (unsigned short)(pv >> 16));
        acc += (float)lo * w[k] + (float)hi * w[k + 1];
    }
    float p = fmaxf(acc, 0.0f) * fc2_w[j];
    #pragma unroll
    for (int off = 32; off; off >>= 1) p += __shfl_down(p, off);
    if (j == 0) out[b] = 1.0f / (1.0f + expf(-(p + fc2_b[0])));
}

extern "C" void kernel_launch(void* const* d_in, const int* in_sizes, int n_in,
                              void* d_out, int out_size, void* d_ws, size_t ws_size,
                              hipStream_t stream) {
    const float* x       = (const float*)d_in[0];
    // d_in[1] = length_list : unused by the reference output
    const float* w_ih_l0 = (const float*)d_in[2];
    const float* w_hh_l0 = (const float*)d_in[3];
    const float* b_ih_l0 = (const float*)d_in[4];
    const float* b_hh_l0 = (const float*)d_in[5];
    const float* w_ih_l1 = (const float*)d_in[6];
    const float* w_hh_l1 = (const float*)d_in[7];
    const float* b_ih_l1 = (const float*)d_in[8];
    const float* b_hh_l1 = (const float*)d_in[9];
    const float* fc_w    = (const float*)d_in[10];
    const float* fc_b    = (const float*)d_in[11];
    const float* fc2_w   = (const float*)d_in[12];
    const float* fc2_b   = (const float*)d_in[13];
    float* out = (float*)d_out;

    // ws: [0,4KB) sync words (barrier, xcc map, flags) | [4KB,+1MB) h0 ring | next 1MB h1 ring
    char* ws = (char*)d_ws;
    unsigned* syncw = (unsigned*)ws;
    _Float16* h0r = (_Float16*)(ws + 4096);
    _Float16* h1r = (_Float16*)(ws + 4096 + RING * RSLOT * sizeof(_Float16));

    zero_ctr<<<1, 512, 0, stream>>>(syncw);
    lstm_persist<<<256, 256, 0, stream>>>(x,
        w_ih_l0, w_hh_l0, b_ih_l0, b_hh_l0,
        w_ih_l1, w_hh_l1, b_ih_l1, b_hh_l1,
        syncw, h0r, h1r);
    // final h1 is at ring slot (1023 & 7) = 7
    fc_kernel<<<Bx, 64, 0, stream>>>(h1r + 7 * RSLOT, fc_w, fc_b, fc2_w, fc2_b, out);
}

// Round 4
// 4571.486 us; speedup vs baseline: 1.0379x; 1.0379x over previous
//
#include <hip/hip_runtime.h>
#include <hip/hip_bf16.h>
#include <stdint.h>

// Problem dims
#define Bx  128
#define Tt  1024
#define INx 256
#define Hx  512
#define RB  16           // batch rows per group
#define RING 8           // h0/h1 ring slots
#define LSTR 520         // LDS A-row stride in fp16 (512 + 8 pad)
#define RSLOT (Bx*Hx)    // ring slot elements (fp16)

// s_getreg encoding: ID | (offset<<6) | ((size-1)<<11); ID_XCC_ID = 20 (gfx94x/gfx950)
#define HWREG_XCC_ID_ENC (20 | (0 << 6) | (31 << 11))

typedef _Float16 half8 __attribute__((ext_vector_type(8)));
typedef float float4v __attribute__((ext_vector_type(4)));

__device__ __forceinline__ float sigf(float x) { return 1.0f / (1.0f + expf(-x)); }

__device__ __forceinline__ half8 cvt8(const float* __restrict__ p) {
    float4v f0 = *(const float4v*)(p);
    float4v f1 = *(const float4v*)(p + 4);
    half8 a;
    a[0] = (_Float16)f0[0]; a[1] = (_Float16)f0[1];
    a[2] = (_Float16)f0[2]; a[3] = (_Float16)f0[3];
    a[4] = (_Float16)f1[0]; a[5] = (_Float16)f1[1];
    a[6] = (_Float16)f1[2]; a[7] = (_Float16)f1[3];
    return a;
}

__device__ __forceinline__ void vm0() { asm volatile("s_waitcnt vmcnt(0)" ::: "memory"); }

// Pin a weight fragment into an AGPR tuple: value becomes asm-defined (cannot be
// rematerialized from its load) and AGPR-classed (keeps arch-VGPR pressure low;
// gfx950 MFMA reads A/B operands directly from AGPRs).
__device__ __forceinline__ void pin(half8& v) { asm volatile("" : "+a"(v)); }

// h-data path.
// L2M=true : all 32 blocks of this group share one XCD -> plain store lands in
//            that XCD's L2 (L1 is write-through); sc0 load bypasses L1, hits L2.
// L2M=false: MALL-coherent (sc0 sc1) -- correct for any placement (baseline).
template<bool L2M>
__device__ __forceinline__ half8 ldq(const _Float16* p) {
    half8 v;
    if (L2M) asm volatile("global_load_dwordx4 %0, %1, off sc0"       : "=v"(v) : "v"(p) : "memory");
    else     asm volatile("global_load_dwordx4 %0, %1, off sc0 sc1"   : "=v"(v) : "v"(p) : "memory");
    return v;
}
template<bool L2M>
__device__ __forceinline__ void stw(void* p, unsigned v) {
    if (L2M) asm volatile("global_store_dword %0, %1, off"            :: "v"(p), "v"(v) : "memory");
    else     asm volatile("global_store_dword %0, %1, off sc0 sc1"    :: "v"(p), "v"(v) : "memory");
}

// Flags: ALWAYS agent-scope atomics at MALL (the proven baseline protocol).
__device__ __forceinline__ unsigned ldctr(const unsigned* p) {
    return __hip_atomic_load(p, __ATOMIC_RELAXED, __HIP_MEMORY_SCOPE_AGENT);
}
__device__ __forceinline__ void stflag(unsigned* p, unsigned v) {
    __hip_atomic_store(p, v, __ATOMIC_RELAXED, __HIP_MEMORY_SCOPE_AGENT);
}

// wave-0 poll: lanes [0,n0) require b0[lane] >= t0 ; lanes [16,16+n1) require b1[lane-16] >= t1
__device__ __forceinline__ void pollge(const unsigned* b0, unsigned t0, int n0,
                                       const unsigned* b1, unsigned t1, int n1, int lane) {
    const unsigned* p = nullptr; unsigned t = 0; int act = 0;
    if (lane < n0)                          { p = b0 + lane;        t = t0; act = 1; }
    else if (lane >= 16 && lane < 16 + n1)  { p = b1 + (lane - 16); t = t1; act = 1; }
    for (;;) {
        int ok = 1;
        if (act) ok = (ldctr(p) >= t);
        if (__all(ok)) break;
        __builtin_amdgcn_s_sleep(1);
    }
}

// A-read once, two MFMAs (2 unit-tiles) per K-chunk.
template<int NC, int NA>
__device__ __forceinline__ void mfma2(const _Float16* buf, int arow, int koff,
                                      const half8 (&B0)[NA], const half8 (&B1)[NA],
                                      float4v& a0, float4v& a1) {
    #pragma unroll
    for (int c = 0; c < NC; ++c) {
        half8 a = *(const half8*)(buf + arow + c * 32 + koff);
        a0 = __builtin_amdgcn_mfma_f32_16x16x32_f16(a, B0[c], a0, 0, 0, 0);
        a1 = __builtin_amdgcn_mfma_f32_16x16x32_f16(a, B1[c], a1, 0, 0, 0);
    }
}

// ws word layout: [0]=startup barrier, [32..287]=xcc map,
// [512..767]=flags (8 groups x {16 L0, 16 L1}; value = last finished step + 1).
// zero_ctr re-zeroes everything at the start of every replay.
__global__ void zero_ctr(unsigned* __restrict__ p) {
    for (int i = threadIdx.x; i < 1024; i += 512)
        __hip_atomic_store(&p[i], 0u, __ATOMIC_RELAXED, __HIP_MEMORY_SCOPE_AGENT);
}

template<bool L2M>
__device__ void run_lstm(
    int g, int id, int tid,
    const float* __restrict__ x,
    const float* __restrict__ w_ih_l0, const float* __restrict__ w_hh_l0,
    const float* __restrict__ b_ih_l0, const float* __restrict__ b_hh_l0,
    const float* __restrict__ w_ih_l1, const float* __restrict__ w_hh_l1,
    const float* __restrict__ b_ih_l1, const float* __restrict__ b_hh_l1,
    unsigned* __restrict__ syncw, _Float16* __restrict__ h0r, _Float16* __restrict__ h1r,
    _Float16* bufX, _Float16* bufH, float (*gbuf)[RB][33])
{
    const int L   = id & 1;
    const int ub  = id >> 1;
    const int u0  = ub * 32;
    const int grow = g * RB;

    const int wv   = tid >> 6;      // gate wave
    const int lane = tid & 63;
    const int n    = lane & 15;
    const int quad = lane >> 4;
    const int koff = quad * 8;
    const int arow = n * LSTR;
    const int srow = tid >> 4;      // staging/update row 0..15
    const int sc   = tid & 15;      // staging col / update unit-pair

    unsigned* flags = syncw + 512;
    unsigned* fl0 = flags + g * 32;           // layer-0 flags [16]
    unsigned* fl1 = flags + g * 32 + 16;      // layer-1 flags [16]
    unsigned* myf = flags + g * 32 + L * 16 + ub;

    // biases for this thread's 2 update units, all 4 gates
    const float* bi = L ? b_ih_l1 : b_ih_l0;
    const float* bh = L ? b_hh_l1 : b_hh_l0;
    float bias[4][2];
    #pragma unroll
    for (int q = 0; q < 4; ++q)
        #pragma unroll
        for (int j = 0; j < 2; ++j) {
            int u = q * Hx + u0 + 2 * sc + j;
            bias[q][j] = bi[u] + bh[u];
        }

    float cs0 = 0.0f, cs1 = 0.0f;   // cell states for the 2 update units

    if (L == 0) {
        // -------- layer 0 --------
        half8 W1a[8], W1b[8], W2a[16], W2b[16];
        const int wrA = wv * Hx + u0 + n, wrB = wrA + 16;
        #pragma unroll
        for (int c = 0; c < 8; ++c) {
            W1a[c] = cvt8(w_ih_l0 + (size_t)wrA * INx + c * 32 + koff);
            W1b[c] = cvt8(w_ih_l0 + (size_t)wrB * INx + c * 32 + koff);
        }
        #pragma unroll
        for (int c = 0; c < 16; ++c) {
            W2a[c] = cvt8(w_hh_l0 + (size_t)wrA * Hx + c * 32 + koff);
            W2b[c] = cvt8(w_hh_l0 + (size_t)wrB * Hx + c * 32 + koff);
        }
        // Pin weights in AGPRs: loaded/converted ONCE, never re-fetched per step.
        #pragma unroll
        for (int c = 0; c < 8; ++c)  { pin(W1a[c]); pin(W1b[c]); }
        #pragma unroll
        for (int c = 0; c < 16; ++c) { pin(W2a[c]); pin(W2b[c]); }

        for (int s = 0; s < Tt; ++s) {
            // stage x_s (cached loads; before the poll barrier)
            {
                const float* xp = x + ((size_t)(grow + srow) * Tt + s) * INx + sc * 16;
                float4v x0 = *(const float4v*)(xp);
                float4v x1 = *(const float4v*)(xp + 4);
                float4v x2 = *(const float4v*)(xp + 8);
                float4v x3 = *(const float4v*)(xp + 12);
                half8 hA, hB;
                hA[0]=(_Float16)x0[0]; hA[1]=(_Float16)x0[1]; hA[2]=(_Float16)x0[2]; hA[3]=(_Float16)x0[3];
                hA[4]=(_Float16)x1[0]; hA[5]=(_Float16)x1[1]; hA[6]=(_Float16)x1[2]; hA[7]=(_Float16)x1[3];
                hB[0]=(_Float16)x2[0]; hB[1]=(_Float16)x2[1]; hB[2]=(_Float16)x2[2]; hB[3]=(_Float16)x2[3];
                hB[4]=(_Float16)x3[0]; hB[5]=(_Float16)x3[1]; hB[6]=(_Float16)x3[2]; hB[7]=(_Float16)x3[3];
                *(half8*)(bufX + srow * LSTR + sc * 16)     = hA;
                *(half8*)(bufX + srow * LSTR + sc * 16 + 8) = hB;
            }
            __syncthreads();                                 // (a) bufX ready
            float4v a0 = {0.f,0.f,0.f,0.f}, a1 = {0.f,0.f,0.f,0.f};
            if (wv != 0) {
                mfma2<8>(bufX, arow, koff, W1a, W1b, a0, a1); // overlap with wave-0 poll
            } else {
                int n0 = (s > 0) ? 16 : 0;                    // peers produced h0[s-1]
                int n1 = (((s & 3) == 0) && s >= 8) ? 16 : 0; // ring guard: L1 finished s-5
                pollge(fl0, (unsigned)s, n0, fl1, (unsigned)(s - 4), n1, lane);
            }
            __syncthreads();                                 // (b) h0[s-1] visible
            if (s > 0) {
                const _Float16* hp = h0r + (size_t)((s - 1) & 7) * RSLOT
                                   + (size_t)(grow + srow) * Hx + sc * 32;
                half8 v0 = ldq<L2M>(hp), v1 = ldq<L2M>(hp + 8),
                      v2 = ldq<L2M>(hp + 16), v3 = ldq<L2M>(hp + 24);
                if (wv == 0) mfma2<8>(bufX, arow, koff, W1a, W1b, a0, a1); // under load latency
                vm0();
                *(half8*)(bufH + srow * LSTR + sc * 32)      = v0;
                *(half8*)(bufH + srow * LSTR + sc * 32 + 8)  = v1;
                *(half8*)(bufH + srow * LSTR + sc * 32 + 16) = v2;
                *(half8*)(bufH + srow * LSTR + sc * 32 + 24) = v3;
                __syncthreads();                             // (c)
                mfma2<16>(bufH, arow, koff, W2a, W2b, a0, a1);
            } else if (wv == 0) {
                mfma2<8>(bufX, arow, koff, W1a, W1b, a0, a1);
            }
            #pragma unroll
            for (int r = 0; r < 4; ++r) {
                gbuf[wv][quad * 4 + r][n]      = a0[r];
                gbuf[wv][quad * 4 + r][16 + n] = a1[r];
            }
            __syncthreads();                                 // (d)
            {
                unsigned pv = 0;
                #pragma unroll
                for (int j = 0; j < 2; ++j) {
                    float iv = gbuf[0][srow][2 * sc + j] + bias[0][j];
                    float fv = gbuf[1][srow][2 * sc + j] + bias[1][j];
                    float gv = gbuf[2][srow][2 * sc + j] + bias[2][j];
                    float ov = gbuf[3][srow][2 * sc + j] + bias[3][j];
                    float& cc = j ? cs1 : cs0;
                    float cn = sigf(fv) * cc + sigf(iv) * tanhf(gv);
                    cc = cn;
                    _Float16 hn = (_Float16)(sigf(ov) * tanhf(cn));
                    pv |= (unsigned)__builtin_bit_cast(unsigned short, hn) << (16 * j);
                }
                stw<L2M>(h0r + (size_t)(s & 7) * RSLOT + (size_t)(grow + srow) * Hx + u0 + 2 * sc, pv);
            }
            vm0();                                           // stores ack'd (L2 in L2M mode)
            __syncthreads();                                 // (e)
            if (tid == 0) stflag(myf, (unsigned)(s + 1));    // flag via MALL (proven path)
        }
    } else {
        // -------- layer 1 --------
        half8 W1a[16], W1b[16], W2a[16], W2b[16];
        const int wrA = wv * Hx + u0 + n, wrB = wrA + 16;
        #pragma unroll
        for (int c = 0; c < 16; ++c) {
            W1a[c] = cvt8(w_ih_l1 + (size_t)wrA * Hx + c * 32 + koff);
            W1b[c] = cvt8(w_ih_l1 + (size_t)wrB * Hx + c * 32 + koff);
            W2a[c] = cvt8(w_hh_l1 + (size_t)wrA * Hx + c * 32 + koff);
            W2b[c] = cvt8(w_hh_l1 + (size_t)wrB * Hx + c * 32 + koff);
        }
        // Pin weights in AGPRs: loaded/converted ONCE, never re-fetched per step.
        #pragma unroll
        for (int c = 0; c < 16; ++c) {
            pin(W1a[c]); pin(W1b[c]); pin(W2a[c]); pin(W2b[c]);
        }

        for (int s = 0; s < Tt; ++s) {
            // phase 1: h0[s] (L0 runs ahead -- usually ready immediately)
            if (wv == 0) pollge(fl0, (unsigned)(s + 1), 16, nullptr, 0u, 0, lane);
            __syncthreads();                                 // (a)
            {
                const _Float16* hp0 = h0r + (size_t)(s & 7) * RSLOT
                                    + (size_t)(grow + srow) * Hx + sc * 32;
                half8 v0 = ldq<L2M>(hp0), v1 = ldq<L2M>(hp0 + 8),
                      v2 = ldq<L2M>(hp0 + 16), v3 = ldq<L2M>(hp0 + 24);
                vm0();
                *(half8*)(bufX + srow * LSTR + sc * 32)      = v0;
                *(half8*)(bufX + srow * LSTR + sc * 32 + 8)  = v1;
                *(half8*)(bufX + srow * LSTR + sc * 32 + 16) = v2;
                *(half8*)(bufX + srow * LSTR + sc * 32 + 24) = v3;
            }
            __syncthreads();                                 // (b)
            float4v a0 = {0.f,0.f,0.f,0.f}, a1 = {0.f,0.f,0.f,0.f};
            if (wv != 0) {
                mfma2<16>(bufX, arow, koff, W1a, W1b, a0, a1); // overlap with h1-wait
            } else if (s > 0) {
                pollge(fl1, (unsigned)s, 16, nullptr, 0u, 0, lane); // peers made h1[s-1]
            }
            __syncthreads();                                 // (c)
            if (s > 0) {
                const _Float16* hp1 = h1r + (size_t)((s - 1) & 7) * RSLOT
                                    + (size_t)(grow + srow) * Hx + sc * 32;
                half8 w0 = ldq<L2M>(hp1), w1 = ldq<L2M>(hp1 + 8),
                      w2 = ldq<L2M>(hp1 + 16), w3 = ldq<L2M>(hp1 + 24);
                if (wv == 0) mfma2<16>(bufX, arow, koff, W1a, W1b, a0, a1);
                vm0();
                *(half8*)(bufH + srow * LSTR + sc * 32)      = w0;
                *(half8*)(bufH + srow * LSTR + sc * 32 + 8)  = w1;
                *(half8*)(bufH + srow * LSTR + sc * 32 + 16) = w2;
                *(half8*)(bufH + srow * LSTR + sc * 32 + 24) = w3;
                __syncthreads();                             // (d)
                mfma2<16>(bufH, arow, koff, W2a, W2b, a0, a1);
            } else if (wv == 0) {
                mfma2<16>(bufX, arow, koff, W1a, W1b, a0, a1);
            }
            #pragma unroll
            for (int r = 0; r < 4; ++r) {
                gbuf[wv][quad * 4 + r][n]      = a0[r];
                gbuf[wv][quad * 4 + r][16 + n] = a1[r];
            }
            __syncthreads();                                 // (e)
            {
                unsigned pv = 0;
                #pragma unroll
                for (int j = 0; j < 2; ++j) {
                    float iv = gbuf[0][srow][2 * sc + j] + bias[0][j];
                    float fv = gbuf[1][srow][2 * sc + j] + bias[1][j];
                    float gv = gbuf[2][srow][2 * sc + j] + bias[2][j];
                    float ov = gbuf[3][srow][2 * sc + j] + bias[3][j];
                    float& cc = j ? cs1 : cs0;
                    float cn = sigf(fv) * cc + sigf(iv) * tanhf(gv);
                    cc = cn;
                    _Float16 hn = (_Float16)(sigf(ov) * tanhf(cn));
                    pv |= (unsigned)__builtin_bit_cast(unsigned short, hn) << (16 * j);
                }
                _Float16* dst = h1r + (size_t)(s & 7) * RSLOT + (size_t)(grow + srow) * Hx + u0 + 2 * sc;
                if (s == Tt - 1) stw<false>(dst, pv);   // final slot: MALL so fc_kernel sees it
                else             stw<L2M>(dst, pv);
            }
            vm0();
            __syncthreads();                                 // (f)
            if (tid == 0) stflag(myf, (unsigned)(s + 1));
        }
    }
}

// Persistent LSTM: 256 blocks x 256 threads (4 waves), 1 block/CU.
// Startup: every block reads XCC_ID (builtin s_getreg), publishes it,
// grid-barriers once, and all blocks deterministically compute the same
// grouping from the shared map. If every XCD holds exactly 32 blocks,
// group = XCD and the h-data exchange runs through that XCD's L2;
// otherwise fall back to the MALL data path. Flags always via MALL.
__global__ __launch_bounds__(256, 1) void lstm_persist(
    const float* __restrict__ x,
    const float* __restrict__ w_ih_l0, const float* __restrict__ w_hh_l0,
    const float* __restrict__ b_ih_l0, const float* __restrict__ b_hh_l0,
    const float* __restrict__ w_ih_l1, const float* __restrict__ w_hh_l1,
    const float* __restrict__ b_ih_l1, const float* __restrict__ b_hh_l1,
    unsigned* __restrict__ syncw,
    _Float16* __restrict__ h0r, _Float16* __restrict__ h1r)
{
    __shared__ _Float16 bufX[RB * LSTR];   // 16.6 KB
    __shared__ _Float16 bufH[RB * LSTR];   // 16.6 KB
    __shared__ float gbuf[4][RB][33];      // 8.4 KB
    __shared__ unsigned smap[256];         // 1 KB
    __shared__ int sh_g, sh_id, sh_valid;

    const int tid = threadIdx.x;
    const int blk = blockIdx.x;

    const unsigned xcc = (unsigned)__builtin_amdgcn_s_getreg(HWREG_XCC_ID_ENC) & 7u;

    if (tid == 0) {
        __hip_atomic_store(&syncw[32 + blk], xcc, __ATOMIC_RELAXED, __HIP_MEMORY_SCOPE_AGENT);
        __hip_atomic_fetch_add(&syncw[0], 1u, __ATOMIC_RELEASE, __HIP_MEMORY_SCOPE_AGENT);
        while (__hip_atomic_load(&syncw[0], __ATOMIC_ACQUIRE, __HIP_MEMORY_SCOPE_AGENT) < 256u)
            __builtin_amdgcn_s_sleep(2);
    }
    __syncthreads();
    smap[tid] = __hip_atomic_load(&syncw[32 + tid], __ATOMIC_RELAXED, __HIP_MEMORY_SCOPE_AGENT);
    __syncthreads();
    if (tid == 0) {
        int cnt[8] = {0,0,0,0,0,0,0,0};
        int rank = 0;
        for (int i = 0; i < 256; ++i) {
            int m = (int)(smap[i] & 7u);
            cnt[m]++;
            if (i < blk && m == (int)xcc) rank++;
        }
        int ok = 1;
        #pragma unroll
        for (int i = 0; i < 8; ++i) ok &= (cnt[i] == 32);
        sh_valid = ok;
        sh_g  = ok ? (int)xcc : (blk >> 5);
        sh_id = ok ? rank : (blk & 31);
    }
    __syncthreads();

    if (sh_valid)
        run_lstm<true >(sh_g, sh_id, tid, x, w_ih_l0, w_hh_l0, b_ih_l0, b_hh_l0,
                        w_ih_l1, w_hh_l1, b_ih_l1, b_hh_l1, syncw, h0r, h1r,
                        bufX, bufH, gbuf);
    else
        run_lstm<false>(sh_g, sh_id, tid, x, w_ih_l0, w_hh_l0, b_ih_l0, b_hh_l0,
                        w_ih_l1, w_hh_l1, b_ih_l1, b_hh_l1, syncw, h0r, h1r,
                        bufX, bufH, gbuf);
}

// FC head; final h1 slot was stored sc0 sc1 (MALL), read with agent atomics.
__global__ __launch_bounds__(64) void fc_kernel(
    const _Float16* __restrict__ h1,
    const float* __restrict__ fc_w, const float* __restrict__ fc_b,
    const float* __restrict__ fc2_w, const float* __restrict__ fc2_b,
    float* __restrict__ out)
{
    const int b = blockIdx.x;
    const int j = threadIdx.x;
    const _Float16* h = h1 + (size_t)b * Hx;
    const float* w = fc_w + (size_t)j * Hx;
    float acc = fc_b[j];
    for (int k = 0; k < Hx; k += 2) {
        unsigned pv = __hip_atomic_load((const unsigned*)(h + k),
                                        __ATOMIC_RELAXED, __HIP_MEMORY_SCOPE_AGENT);
        _Float16 lo = __builtin_bit_cast(_Float16, (unsigned short)(pv & 0xffffu));
        _Float16 hi = __builtin_bit_cast(_Float16, (unsigned short)(pv >> 16));
        acc += (float)lo * w[k] + (float)hi * w[k + 1];
    }
    float p = fmaxf(acc, 0.0f) * fc2_w[j];
    #pragma unroll
    for (int off = 32; off; off >>= 1) p += __shfl_down(p, off);
    if (j == 0) out[b] = 1.0f / (1.0f + expf(-(p + fc2_b[0])));
}

extern "C" void kernel_launch(void* const* d_in, const int* in_sizes, int n_in,
                              void* d_out, int out_size, void* d_ws, size_t ws_size,
                              hipStream_t stream) {
    const float* x       = (const float*)d_in[0];
    // d_in[1] = length_list : unused by the reference output
    const float* w_ih_l0 = (const float*)d_in[2];
    const float* w_hh_l0 = (const float*)d_in[3];
    const float* b_ih_l0 = (const float*)d_in[4];
    const float* b_hh_l0 = (const float*)d_in[5];
    const float* w_ih_l1 = (const float*)d_in[6];
    const float* w_hh_l1 = (const float*)d_in[7];
    const float* b_ih_l1 = (const float*)d_in[8];
    const float* b_hh_l1 = (const float*)d_in[9];
    const float* fc_w    = (const float*)d_in[10];
    const float* fc_b    = (const float*)d_in[11];
    const float* fc2_w   = (const float*)d_in[12];
    const float* fc2_b   = (const float*)d_in[13];
    float* out = (float*)d_out;

    // ws: [0,4KB) sync words (barrier, xcc map, flags) | [4KB,+1MB) h0 ring | next 1MB h1 ring
    char* ws = (char*)d_ws;
    unsigned* syncw = (unsigned*)ws;
    _Float16* h0r = (_Float16*)(ws + 4096);
    _Float16* h1r = (_Float16*)(ws + 4096 + RING * RSLOT * sizeof(_Float16));

    zero_ctr<<<1, 512, 0, stream>>>(syncw);
    lstm_persist<<<256, 256, 0, stream>>>(x,
        w_ih_l0, w_hh_l0, b_ih_l0, b_hh_l0,
        w_ih_l1, w_hh_l1, b_ih_l1, b_hh_l1,
        syncw, h0r, h1r);
    // final h1 is at ring slot (1023 & 7) = 7
    fc_kernel<<<Bx, 64, 0, stream>>>(h1r + 7 * RSLOT, fc_w, fc_b, fc2_w, fc2_b, out);
}

// Round 6
// 3733.861 us; speedup vs baseline: 1.2708x; 1.2243x over previous
//
#include <hip/hip_runtime.h>
#include <hip/hip_bf16.h>
#include <stdint.h>

// Problem dims
#define Bx  128
#define Tt  1024
#define INx 256
#define Hx  512
#define RB  16           // batch rows per group
#define RING 8           // h0/h1 ring slots
#define LSTR 520         // LDS A-row stride in fp16 (512 + 8 pad)
#define RSLOT (Bx*Hx)    // ring slot elements (fp16)

// s_getreg encoding: ID | (offset<<6) | ((size-1)<<11); ID_XCC_ID = 20 (gfx94x/gfx950)
#define HWREG_XCC_ID_ENC (20 | (0 << 6) | (31 << 11))

typedef _Float16 half8 __attribute__((ext_vector_type(8)));
typedef float float4v __attribute__((ext_vector_type(4)));

__device__ __forceinline__ float sigf(float x) { return 1.0f / (1.0f + expf(-x)); }

__device__ __forceinline__ half8 cvt8(const float* __restrict__ p) {
    float4v f0 = *(const float4v*)(p);
    float4v f1 = *(const float4v*)(p + 4);
    half8 a;
    a[0] = (_Float16)f0[0]; a[1] = (_Float16)f0[1];
    a[2] = (_Float16)f0[2]; a[3] = (_Float16)f0[3];
    a[4] = (_Float16)f1[0]; a[5] = (_Float16)f1[1];
    a[6] = (_Float16)f1[2]; a[7] = (_Float16)f1[3];
    return a;
}

__device__ __forceinline__ void vm0() { asm volatile("s_waitcnt vmcnt(0)" ::: "memory"); }

// Pin a weight fragment into an AGPR tuple: value becomes asm-defined (cannot be
// rematerialized from its load) and AGPR-classed. Verified round 4: VGPR 176->256,
// weights stay resident across the whole T-loop.
__device__ __forceinline__ void pin(half8& v) { asm volatile("" : "+a"(v)); }

// h-data path.
// L2M=true : all 32 blocks of this group share one XCD -> plain store lands in
//            that XCD's L2 (L1 is write-through); sc0 load bypasses L1, hits L2.
// L2M=false: MALL-coherent (sc0 sc1) -- correct for any placement (baseline).
template<bool L2M>
__device__ __forceinline__ half8 ldq(const _Float16* p) {
    half8 v;
    if (L2M) asm volatile("global_load_dwordx4 %0, %1, off sc0"       : "=v"(v) : "v"(p) : "memory");
    else     asm volatile("global_load_dwordx4 %0, %1, off sc0 sc1"   : "=v"(v) : "v"(p) : "memory");
    return v;
}
template<bool L2M>
__device__ __forceinline__ void stw(void* p, unsigned v) {
    if (L2M) asm volatile("global_store_dword %0, %1, off"            :: "v"(p), "v"(v) : "memory");
    else     asm volatile("global_store_dword %0, %1, off sc0 sc1"    :: "v"(p), "v"(v) : "memory");
}

// Flag reads: L2 fast path (sc0, same-XCD dirty-line hit) and MALL ground truth
// (sc0 sc1). The poll alternates them so no staleness corner can spin forever.
__device__ __forceinline__ unsigned ldf_l2(const unsigned* p) {
    unsigned v;
    asm volatile("global_load_dword %0, %1, off sc0\n\ts_waitcnt vmcnt(0)"
                 : "=v"(v) : "v"(p) : "memory");
    return v;
}
__device__ __forceinline__ unsigned ldf_mall(const unsigned* p) {
    unsigned v;
    asm volatile("global_load_dword %0, %1, off sc0 sc1\n\ts_waitcnt vmcnt(0)"
                 : "=v"(v) : "v"(p) : "memory");
    return v;
}
// Flag store: L2M = plain store (visible to same-XCD sc0 readers in ~100cy);
// fallback = MALL write-through (baseline protocol).
template<bool L2M>
__device__ __forceinline__ void stflag(unsigned* p, unsigned v) {
    if (L2M) asm volatile("global_store_dword %0, %1, off"         :: "v"(p), "v"(v) : "memory");
    else     asm volatile("global_store_dword %0, %1, off sc0 sc1" :: "v"(p), "v"(v) : "memory");
}

// wave-0 poll: lanes [0,n0) require b0[lane] >= t0 ; lanes [16,16+n1) require b1[lane-16] >= t1.
// Iteration alternates L2 read / MALL read (L2M) so progress never depends on a
// single cache path; s_sleep(1) throttles to avoid read-storm arbitration corners.
template<bool L2M>
__device__ __forceinline__ void pollge(const unsigned* b0, unsigned t0, int n0,
                                       const unsigned* b1, unsigned t1, int n1, int lane) {
    const unsigned* p = nullptr; unsigned t = 0; int act = 0;
    if (lane < n0)                          { p = b0 + lane;        t = t0; act = 1; }
    else if (lane >= 16 && lane < 16 + n1)  { p = b1 + (lane - 16); t = t1; act = 1; }
    unsigned it = 0;
    for (;;) {
        int ok = 1;
        if (act) {
            unsigned v = (L2M && !(it & 1)) ? ldf_l2(p) : ldf_mall(p);
            ok = (v >= t);
        }
        if (__all(ok)) break;
        ++it;
        __builtin_amdgcn_s_sleep(1);
    }
}

// A-read once, two MFMAs (2 unit-tiles) per K-chunk.
template<int NC, int NA>
__device__ __forceinline__ void mfma2(const _Float16* buf, int arow, int koff,
                                      const half8 (&B0)[NA], const half8 (&B1)[NA],
                                      float4v& a0, float4v& a1) {
    #pragma unroll
    for (int c = 0; c < NC; ++c) {
        half8 a = *(const half8*)(buf + arow + c * 32 + koff);
        a0 = __builtin_amdgcn_mfma_f32_16x16x32_f16(a, B0[c], a0, 0, 0, 0);
        a1 = __builtin_amdgcn_mfma_f32_16x16x32_f16(a, B1[c], a1, 0, 0, 0);
    }
}

// ws word layout: [0]=startup barrier, [32..287]=xcc map,
// [512..767]=flags (8 groups x {16 L0, 16 L1}; value = last finished step + 1).
// zero_ctr re-zeroes everything at the start of every replay.
__global__ void zero_ctr(unsigned* __restrict__ p) {
    for (int i = threadIdx.x; i < 1024; i += 512)
        __hip_atomic_store(&p[i], 0u, __ATOMIC_RELAXED, __HIP_MEMORY_SCOPE_AGENT);
}

template<bool L2M>
__device__ void run_lstm(
    int g, int id, int tid,
    const float* __restrict__ x,
    const float* __restrict__ w_ih_l0, const float* __restrict__ w_hh_l0,
    const float* __restrict__ b_ih_l0, const float* __restrict__ b_hh_l0,
    const float* __restrict__ w_ih_l1, const float* __restrict__ w_hh_l1,
    const float* __restrict__ b_ih_l1, const float* __restrict__ b_hh_l1,
    unsigned* __restrict__ syncw, _Float16* __restrict__ h0r, _Float16* __restrict__ h1r,
    _Float16* bufX, _Float16* bufH, float (*gbuf)[RB][33])
{
    const int L   = id & 1;
    const int ub  = id >> 1;
    const int u0  = ub * 32;
    const int grow = g * RB;

    const int wv   = tid >> 6;      // gate wave
    const int lane = tid & 63;
    const int n    = lane & 15;
    const int quad = lane >> 4;
    const int koff = quad * 8;
    const int arow = n * LSTR;
    const int srow = tid >> 4;      // staging/update row 0..15
    const int sc   = tid & 15;      // staging col / update unit-pair

    unsigned* flags = syncw + 512;
    unsigned* fl0 = flags + g * 32;           // layer-0 flags [16]
    unsigned* fl1 = flags + g * 32 + 16;      // layer-1 flags [16]
    unsigned* myf = flags + g * 32 + L * 16 + ub;

    // biases for this thread's 2 update units, all 4 gates
    const float* bi = L ? b_ih_l1 : b_ih_l0;
    const float* bh = L ? b_hh_l1 : b_hh_l0;
    float bias[4][2];
    #pragma unroll
    for (int q = 0; q < 4; ++q)
        #pragma unroll
        for (int j = 0; j < 2; ++j) {
            int u = q * Hx + u0 + 2 * sc + j;
            bias[q][j] = bi[u] + bh[u];
        }

    float cs0 = 0.0f, cs1 = 0.0f;   // cell states for the 2 update units

    if (L == 0) {
        // -------- layer 0 --------
        half8 W1a[8], W1b[8], W2a[16], W2b[16];
        const int wrA = wv * Hx + u0 + n, wrB = wrA + 16;
        #pragma unroll
        for (int c = 0; c < 8; ++c) {
            W1a[c] = cvt8(w_ih_l0 + (size_t)wrA * INx + c * 32 + koff);
            W1b[c] = cvt8(w_ih_l0 + (size_t)wrB * INx + c * 32 + koff);
        }
        #pragma unroll
        for (int c = 0; c < 16; ++c) {
            W2a[c] = cvt8(w_hh_l0 + (size_t)wrA * Hx + c * 32 + koff);
            W2b[c] = cvt8(w_hh_l0 + (size_t)wrB * Hx + c * 32 + koff);
        }
        // Pin weights in AGPRs: loaded/converted ONCE, never re-fetched per step.
        #pragma unroll
        for (int c = 0; c < 8; ++c)  { pin(W1a[c]); pin(W1b[c]); }
        #pragma unroll
        for (int c = 0; c < 16; ++c) { pin(W2a[c]); pin(W2b[c]); }

        // x software prefetch: registers hold x_s while x_{s+1} loads in flight.
        const float* xrp = x + ((size_t)(grow + srow) * Tt) * INx + sc * 16;
        float4v xr0 = *(const float4v*)(xrp);
        float4v xr1 = *(const float4v*)(xrp + 4);
        float4v xr2 = *(const float4v*)(xrp + 8);
        float4v xr3 = *(const float4v*)(xrp + 12);

        for (int s = 0; s < Tt; ++s) {
            // stage x_s from prefetched registers (no memory wait here)
            {
                half8 hA, hB;
                hA[0]=(_Float16)xr0[0]; hA[1]=(_Float16)xr0[1]; hA[2]=(_Float16)xr0[2]; hA[3]=(_Float16)xr0[3];
                hA[4]=(_Float16)xr1[0]; hA[5]=(_Float16)xr1[1]; hA[6]=(_Float16)xr1[2]; hA[7]=(_Float16)xr1[3];
                hB[0]=(_Float16)xr2[0]; hB[1]=(_Float16)xr2[1]; hB[2]=(_Float16)xr2[2]; hB[3]=(_Float16)xr2[3];
                hB[4]=(_Float16)xr3[0]; hB[5]=(_Float16)xr3[1]; hB[6]=(_Float16)xr3[2]; hB[7]=(_Float16)xr3[3];
                *(half8*)(bufX + srow * LSTR + sc * 16)     = hA;
                *(half8*)(bufX + srow * LSTR + sc * 16 + 8) = hB;
            }
            __syncthreads();                                 // (a) bufX ready
            // issue x_{s+1} loads now; they complete under this step's work
            if (s + 1 < Tt) {
                const float* xp = xrp + (size_t)(s + 1) * INx;
                xr0 = *(const float4v*)(xp);
                xr1 = *(const float4v*)(xp + 4);
                xr2 = *(const float4v*)(xp + 8);
                xr3 = *(const float4v*)(xp + 12);
            }
            float4v a0 = {0.f,0.f,0.f,0.f}, a1 = {0.f,0.f,0.f,0.f};
            if (wv != 0) {
                mfma2<8>(bufX, arow, koff, W1a, W1b, a0, a1); // overlap with wave-0 poll
            } else {
                int n0 = (s > 0) ? 16 : 0;                    // peers produced h0[s-1]
                int n1 = (((s & 3) == 0) && s >= 8) ? 16 : 0; // ring guard: L1 finished s-5
                pollge<L2M>(fl0, (unsigned)s, n0, fl1, (unsigned)(s - 4), n1, lane);
            }
            __syncthreads();                                 // (b) h0[s-1] visible
            if (s > 0) {
                const _Float16* hp = h0r + (size_t)((s - 1) & 7) * RSLOT
                                   + (size_t)(grow + srow) * Hx + sc * 32;
                half8 v0 = ldq<L2M>(hp), v1 = ldq<L2M>(hp + 8),
                      v2 = ldq<L2M>(hp + 16), v3 = ldq<L2M>(hp + 24);
                if (wv == 0) mfma2<8>(bufX, arow, koff, W1a, W1b, a0, a1); // under load latency
                vm0();
                *(half8*)(bufH + srow * LSTR + sc * 32)      = v0;
                *(half8*)(bufH + srow * LSTR + sc * 32 + 8)  = v1;
                *(half8*)(bufH + srow * LSTR + sc * 32 + 16) = v2;
                *(half8*)(bufH + srow * LSTR + sc * 32 + 24) = v3;
                __syncthreads();                             // (c)
                mfma2<16>(bufH, arow, koff, W2a, W2b, a0, a1);
            } else if (wv == 0) {
                mfma2<8>(bufX, arow, koff, W1a, W1b, a0, a1);
            }
            #pragma unroll
            for (int r = 0; r < 4; ++r) {
                gbuf[wv][quad * 4 + r][n]      = a0[r];
                gbuf[wv][quad * 4 + r][16 + n] = a1[r];
            }
            __syncthreads();                                 // (d)
            {
                unsigned pv = 0;
                #pragma unroll
                for (int j = 0; j < 2; ++j) {
                    float iv = gbuf[0][srow][2 * sc + j] + bias[0][j];
                    float fv = gbuf[1][srow][2 * sc + j] + bias[1][j];
                    float gv = gbuf[2][srow][2 * sc + j] + bias[2][j];
                    float ov = gbuf[3][srow][2 * sc + j] + bias[3][j];
                    float& cc = j ? cs1 : cs0;
                    float cn = sigf(fv) * cc + sigf(iv) * tanhf(gv);
                    cc = cn;
                    _Float16 hn = (_Float16)(sigf(ov) * tanhf(cn));
                    pv |= (unsigned)__builtin_bit_cast(unsigned short, hn) << (16 * j);
                }
                stw<L2M>(h0r + (size_t)(s & 7) * RSLOT + (size_t)(grow + srow) * Hx + u0 + 2 * sc, pv);
            }
            vm0();                                           // stores ack'd (L2 in L2M mode)
            __syncthreads();                                 // (e)
            if (tid == 0) stflag<L2M>(myf, (unsigned)(s + 1));
        }
    } else {
        // -------- layer 1 --------
        half8 W1a[16], W1b[16], W2a[16], W2b[16];
        const int wrA = wv * Hx + u0 + n, wrB = wrA + 16;
        #pragma unroll
        for (int c = 0; c < 16; ++c) {
            W1a[c] = cvt8(w_ih_l1 + (size_t)wrA * Hx + c * 32 + koff);
            W1b[c] = cvt8(w_ih_l1 + (size_t)wrB * Hx + c * 32 + koff);
            W2a[c] = cvt8(w_hh_l1 + (size_t)wrA * Hx + c * 32 + koff);
            W2b[c] = cvt8(w_hh_l1 + (size_t)wrB * Hx + c * 32 + koff);
        }
        // Pin weights in AGPRs: loaded/converted ONCE, never re-fetched per step.
        #pragma unroll
        for (int c = 0; c < 16; ++c) {
            pin(W1a[c]); pin(W1b[c]); pin(W2a[c]); pin(W2b[c]);
        }

        for (int s = 0; s < Tt; ++s) {
            // phase 1: h0[s] (L0 runs ahead -- usually ready immediately)
            if (wv == 0) pollge<L2M>(fl0, (unsigned)(s + 1), 16, nullptr, 0u, 0, lane);
            __syncthreads();                                 // (a)
            {
                const _Float16* hp0 = h0r + (size_t)(s & 7) * RSLOT
                                    + (size_t)(grow + srow) * Hx + sc * 32;
                half8 v0 = ldq<L2M>(hp0), v1 = ldq<L2M>(hp0 + 8),
                      v2 = ldq<L2M>(hp0 + 16), v3 = ldq<L2M>(hp0 + 24);
                vm0();
                *(half8*)(bufX + srow * LSTR + sc * 32)      = v0;
                *(half8*)(bufX + srow * LSTR + sc * 32 + 8)  = v1;
                *(half8*)(bufX + srow * LSTR + sc * 32 + 16) = v2;
                *(half8*)(bufX + srow * LSTR + sc * 32 + 24) = v3;
            }
            __syncthreads();                                 // (b)
            float4v a0 = {0.f,0.f,0.f,0.f}, a1 = {0.f,0.f,0.f,0.f};
            if (wv != 0) {
                mfma2<16>(bufX, arow, koff, W1a, W1b, a0, a1); // overlap with h1-wait
            } else if (s > 0) {
                pollge<L2M>(fl1, (unsigned)s, 16, nullptr, 0u, 0, lane); // peers made h1[s-1]
            }
            __syncthreads();                                 // (c)
            if (s > 0) {
                const _Float16* hp1 = h1r + (size_t)((s - 1) & 7) * RSLOT
                                    + (size_t)(grow + srow) * Hx + sc * 32;
                half8 w0 = ldq<L2M>(hp1), w1 = ldq<L2M>(hp1 + 8),
                      w2 = ldq<L2M>(hp1 + 16), w3 = ldq<L2M>(hp1 + 24);
                if (wv == 0) mfma2<16>(bufX, arow, koff, W1a, W1b, a0, a1);
                vm0();
                *(half8*)(bufH + srow * LSTR + sc * 32)      = w0;
                *(half8*)(bufH + srow * LSTR + sc * 32 + 8)  = w1;
                *(half8*)(bufH + srow * LSTR + sc * 32 + 16) = w2;
                *(half8*)(bufH + srow * LSTR + sc * 32 + 24) = w3;
                __syncthreads();                             // (d)
                mfma2<16>(bufH, arow, koff, W2a, W2b, a0, a1);
            } else if (wv == 0) {
                mfma2<16>(bufX, arow, koff, W1a, W1b, a0, a1);
            }
            #pragma unroll
            for (int r = 0; r < 4; ++r) {
                gbuf[wv][quad * 4 + r][n]      = a0[r];
                gbuf[wv][quad * 4 + r][16 + n] = a1[r];
            }
            __syncthreads();                                 // (e)
            {
                unsigned pv = 0;
                #pragma unroll
                for (int j = 0; j < 2; ++j) {
                    float iv = gbuf[0][srow][2 * sc + j] + bias[0][j];
                    float fv = gbuf[1][srow][2 * sc + j] + bias[1][j];
                    float gv = gbuf[2][srow][2 * sc + j] + bias[2][j];
                    float ov = gbuf[3][srow][2 * sc + j] + bias[3][j];
                    float& cc = j ? cs1 : cs0;
                    float cn = sigf(fv) * cc + sigf(iv) * tanhf(gv);
                    cc = cn;
                    _Float16 hn = (_Float16)(sigf(ov) * tanhf(cn));
                    pv |= (unsigned)__builtin_bit_cast(unsigned short, hn) << (16 * j);
                }
                _Float16* dst = h1r + (size_t)(s & 7) * RSLOT + (size_t)(grow + srow) * Hx + u0 + 2 * sc;
                if (s == Tt - 1) stw<false>(dst, pv);   // final slot: MALL so fc_kernel sees it
                else             stw<L2M>(dst, pv);
            }
            vm0();
            __syncthreads();                                 // (f)
            if (tid == 0) stflag<L2M>(myf, (unsigned)(s + 1));
        }
    }
}

// Persistent LSTM: 256 blocks x 256 threads (4 waves), 1 block/CU.
// Startup census: every block reads XCC_ID, publishes it, grid-barriers once,
// and all blocks deterministically compute the same grouping from the shared
// map. If every XCD holds exactly 32 blocks, group = XCD and both h-data and
// flags run through that XCD's L2 (with MALL-alternating polls for robustness);
// otherwise fall back to the MALL protocol for both.
__global__ __launch_bounds__(256, 1) void lstm_persist(
    const float* __restrict__ x,
    const float* __restrict__ w_ih_l0, const float* __restrict__ w_hh_l0,
    const float* __restrict__ b_ih_l0, const float* __restrict__ b_hh_l0,
    const float* __restrict__ w_ih_l1, const float* __restrict__ w_hh_l1,
    const float* __restrict__ b_ih_l1, const float* __restrict__ b_hh_l1,
    unsigned* __restrict__ syncw,
    _Float16* __restrict__ h0r, _Float16* __restrict__ h1r)
{
    __shared__ _Float16 bufX[RB * LSTR];   // 16.6 KB
    __shared__ _Float16 bufH[RB * LSTR];   // 16.6 KB
    __shared__ float gbuf[4][RB][33];      // 8.4 KB
    __shared__ unsigned smap[256];         // 1 KB
    __shared__ int sh_g, sh_id, sh_valid;

    const int tid = threadIdx.x;
    const int blk = blockIdx.x;

    const unsigned xcc = (unsigned)__builtin_amdgcn_s_getreg(HWREG_XCC_ID_ENC) & 7u;

    if (tid == 0) {
        __hip_atomic_store(&syncw[32 + blk], xcc, __ATOMIC_RELAXED, __HIP_MEMORY_SCOPE_AGENT);
        __hip_atomic_fetch_add(&syncw[0], 1u, __ATOMIC_RELEASE, __HIP_MEMORY_SCOPE_AGENT);
        while (__hip_atomic_load(&syncw[0], __ATOMIC_ACQUIRE, __HIP_MEMORY_SCOPE_AGENT) < 256u)
            __builtin_amdgcn_s_sleep(2);
    }
    __syncthreads();
    smap[tid] = __hip_atomic_load(&syncw[32 + tid], __ATOMIC_RELAXED, __HIP_MEMORY_SCOPE_AGENT);
    __syncthreads();
    if (tid == 0) {
        int cnt[8] = {0,0,0,0,0,0,0,0};
        int rank = 0;
        for (int i = 0; i < 256; ++i) {
            int m = (int)(smap[i] & 7u);
            cnt[m]++;
            if (i < blk && m == (int)xcc) rank++;
        }
        int ok = 1;
        #pragma unroll
        for (int i = 0; i < 8; ++i) ok &= (cnt[i] == 32);
        sh_valid = ok;
        sh_g  = ok ? (int)xcc : (blk >> 5);
        sh_id = ok ? rank : (blk & 31);
    }
    __syncthreads();

    if (sh_valid)
        run_lstm<true >(sh_g, sh_id, tid, x, w_ih_l0, w_hh_l0, b_ih_l0, b_hh_l0,
                        w_ih_l1, w_hh_l1, b_ih_l1, b_hh_l1, syncw, h0r, h1r,
                        bufX, bufH, gbuf);
    else
        run_lstm<false>(sh_g, sh_id, tid, x, w_ih_l0, w_hh_l0, b_ih_l0, b_hh_l0,
                        w_ih_l1, w_hh_l1, b_ih_l1, b_hh_l1, syncw, h0r, h1r,
                        bufX, bufH, gbuf);
}

// FC head; final h1 slot was stored sc0 sc1 (MALL), read with agent atomics.
__global__ __launch_bounds__(64) void fc_kernel(
    const _Float16* __restrict__ h1,
    const float* __restrict__ fc_w, const float* __restrict__ fc_b,
    const float* __restrict__ fc2_w, const float* __restrict__ fc2_b,
    float* __restrict__ out)
{
    const int b = blockIdx.x;
    const int j = threadIdx.x;
    const _Float16* h = h1 + (size_t)b * Hx;
    const float* w = fc_w + (size_t)j * Hx;
    float acc = fc_b[j];
    for (int k = 0; k < Hx; k += 2) {
        unsigned pv = __hip_atomic_load((const unsigned*)(h + k),
                                        __ATOMIC_RELAXED, __HIP_MEMORY_SCOPE_AGENT);
        _Float16 lo = __builtin_bit_cast(_Float16, (unsigned short)(pv & 0xffffu));
        _Float16 hi = __builtin_bit_cast(_Float16, (unsigned short)(pv >> 16));
        acc += (float)lo * w[k] + (float)hi * w[k + 1];
    }
    float p = fmaxf(acc, 0.0f) * fc2_w[j];
    #pragma unroll
    for (int off = 32; off; off >>= 1) p += __shfl_down(p, off);
    if (j == 0) out[b] = 1.0f / (1.0f + expf(-(p + fc2_b[0])));
}

extern "C" void kernel_launch(void* const* d_in, const int* in_sizes, int n_in,
                              void* d_out, int out_size, void* d_ws, size_t ws_size,
                              hipStream_t stream) {
    const float* x       = (const float*)d_in[0];
    // d_in[1] = length_list : unused by the reference output
    const float* w_ih_l0 = (const float*)d_in[2];
    const float* w_hh_l0 = (const float*)d_in[3];
    const float* b_ih_l0 = (const float*)d_in[4];
    const float* b_hh_l0 = (const float*)d_in[5];
    const float* w_ih_l1 = (const float*)d_in[6];
    const float* w_hh_l1 = (const float*)d_in[7];
    const float* b_ih_l1 = (const float*)d_in[8];
    const float* b_hh_l1 = (const float*)d_in[9];
    const float* fc_w    = (const float*)d_in[10];
    const float* fc_b    = (const float*)d_in[11];
    const float* fc2_w   = (const float*)d_in[12];
    const float* fc2_b   = (const float*)d_in[13];
    float* out = (float*)d_out;

    // ws: [0,4KB) sync words (barrier, xcc map, flags) | [4KB,+1MB) h0 ring | next 1MB h1 ring
    char* ws = (char*)d_ws;
    unsigned* syncw = (unsigned*)ws;
    _Float16* h0r = (_Float16*)(ws + 4096);
    _Float16* h1r = (_Float16*)(ws + 4096 + RING * RSLOT * sizeof(_Float16));

    zero_ctr<<<1, 512, 0, stream>>>(syncw);
    lstm_persist<<<256, 256, 0, stream>>>(x,
        w_ih_l0, w_hh_l0, b_ih_l0, b_hh_l0,
        w_ih_l1, w_hh_l1, b_ih_l1, b_hh_l1,
        syncw, h0r, h1r);
    // final h1 is at ring slot (1023 & 7) = 7
    fc_kernel<<<Bx, 64, 0, stream>>>(h1r + 7 * RSLOT, fc_w, fc_b, fc2_w, fc2_b, out);
}